// Round 9
// baseline (140.406 us; speedup 1.0000x reference)
//
#include <hip/hip_runtime.h>

#define D_FEAT 128

typedef unsigned int u32;

__device__ __forceinline__ u32 f2bf_pack(float a, float b) {
    u32 ua = __float_as_uint(a);
    u32 ub = __float_as_uint(b);
    ua = (ua + 0x7fffu + ((ua >> 16) & 1u)) >> 16;   // RNE to bf16
    ub = (ub + 0x7fffu + ((ub >> 16) & 1u)) >> 16;
    return ua | (ub << 16);
}

__device__ __forceinline__ float bf_lo(u32 p) { return __uint_as_float(p << 16); }
__device__ __forceinline__ float bf_hi(u32 p) { return __uint_as_float(p & 0xffff0000u); }

// K0: zero the histogram
__global__ void zero_counts(int* __restrict__ counts, int n) {
    int i = blockIdx.x * 256 + threadIdx.x;
    if (i < n) counts[i] = 0;
}

// K1: histogram with FIRE-AND-FORGET atomics (no return -> no latency stall),
// int4-vectorized edge reads; hn = bf16(h*norm) precompute fused in.
__global__ void deg_hn(const int* __restrict__ dst, int* __restrict__ counts,
                       const float* __restrict__ h, const float* __restrict__ norm,
                       u32* __restrict__ hn, int n_edges, int n_nodes) {
    int gsize = gridDim.x * 256;
    int t = blockIdx.x * 256 + threadIdx.x;
    int e4 = n_edges >> 2;                 // # of full int4 groups
    if (t < e4) {
        int4 d4 = reinterpret_cast<const int4*>(dst)[t];
        atomicAdd(&counts[d4.x], 1);
        atomicAdd(&counts[d4.y], 1);
        atomicAdd(&counts[d4.z], 1);
        atomicAdd(&counts[d4.w], 1);
    } else if (t == e4) {                  // tail (n_edges % 4 edges)
        for (int i = e4 * 4; i < n_edges; ++i) atomicAdd(&counts[dst[i]], 1);
    }
    int total4 = n_nodes * (D_FEAT / 4);
    for (int j = t; j < total4; j += gsize) {
        int node = j >> 5;
        float nm = norm[node];
        float4 v = reinterpret_cast<const float4*>(h)[j];
        uint2 o;
        o.x = f2bf_pack(v.x * nm, v.y * nm);
        o.y = f2bf_pack(v.z * nm, v.w * nm);
        reinterpret_cast<uint2*>(hn)[j] = o;
    }
}

// K2: one-dispatch exclusive scan; block b re-sums chunks [0,b) for its carry,
// then scans its own 1024-elem chunk. Writes FINAL offs and mirrors to cursor.
__global__ void __launch_bounds__(1024)
scan_onepass(const int* __restrict__ counts, int* __restrict__ offs,
             int* __restrict__ cursor, int n, int nb) {
    __shared__ int smem[1024];
    int tid = threadIdx.x;
    int b = blockIdx.x;
    int lim = b << 10;
    int part = 0;
    for (int j = tid; j < lim; j += 1024) part += counts[j];
    smem[tid] = part;
    __syncthreads();
    for (int off = 512; off > 0; off >>= 1) {
        if (tid < off) smem[tid] += smem[tid + off];
        __syncthreads();
    }
    int carry = smem[0];
    __syncthreads();
    int idx = lim + tid;
    int v = (idx < n) ? counts[idx] : 0;
    smem[tid] = v;
    __syncthreads();
    for (int off = 1; off < 1024; off <<= 1) {
        int t = (tid >= off) ? smem[tid - off] : 0;
        __syncthreads();
        smem[tid] += t;
        __syncthreads();
    }
    if (idx < n) {
        int ex = carry + smem[tid] - v;
        offs[idx] = ex;
        cursor[idx] = ex;
    }
    if (b == nb - 1 && tid == 1023) offs[n] = carry + smem[1023];
}

// K3: scatter with atomic cursor, 4 edges/thread (int4 loads) -> 4 independent
// return-atomics in flight per thread (4x MLP on the ~800cy round trip).
__global__ void scatter_csr4(const int* __restrict__ src, const int* __restrict__ dst,
                             int* __restrict__ cursor, int* __restrict__ csr_src,
                             int n_edges) {
    int t = blockIdx.x * 256 + threadIdx.x;
    int e4 = n_edges >> 2;
    if (t < e4) {
        int4 d4 = reinterpret_cast<const int4*>(dst)[t];
        int4 s4 = reinterpret_cast<const int4*>(src)[t];
        int p0 = atomicAdd(&cursor[d4.x], 1);
        int p1 = atomicAdd(&cursor[d4.y], 1);
        int p2 = atomicAdd(&cursor[d4.z], 1);
        int p3 = atomicAdd(&cursor[d4.w], 1);
        csr_src[p0] = s4.x;
        csr_src[p1] = s4.y;
        csr_src[p2] = s4.z;
        csr_src[p3] = s4.w;
    } else if (t == e4) {
        for (int i = e4 * 4; i < n_edges; ++i) {
            int p = atomicAdd(&cursor[dst[i]], 1);
            csr_src[p] = src[i];
        }
    }
}

// K4: gather. 32 lanes per node (2 nodes/wave), uint2 per lane = full 256B
// bf16 row per instruction; unroll 8.
__global__ void gather_bf16_v3(const float* __restrict__ h,
                               const float* __restrict__ norm,
                               const float* __restrict__ eps,
                               const int* __restrict__ offs,
                               const int* __restrict__ csr_src,
                               const u32* __restrict__ hn,
                               float* __restrict__ out, int n_nodes) {
    int t = blockIdx.x * 256 + threadIdx.x;
    int node = t >> 5;
    int lane = t & 31;
    if (node >= n_nodes) return;
    int beg = offs[node];
    int end = offs[node + 1];
    float a0 = 0.0f, a1 = 0.0f, a2 = 0.0f, a3 = 0.0f;
    int i = beg;
    for (; i + 8 <= end; i += 8) {
        int s0 = csr_src[i + 0], s1 = csr_src[i + 1];
        int s2 = csr_src[i + 2], s3 = csr_src[i + 3];
        int s4 = csr_src[i + 4], s5 = csr_src[i + 5];
        int s6 = csr_src[i + 6], s7 = csr_src[i + 7];
        uint2 p0 = reinterpret_cast<const uint2*>(hn + (size_t)s0 * 64)[lane];
        uint2 p1 = reinterpret_cast<const uint2*>(hn + (size_t)s1 * 64)[lane];
        uint2 p2 = reinterpret_cast<const uint2*>(hn + (size_t)s2 * 64)[lane];
        uint2 p3 = reinterpret_cast<const uint2*>(hn + (size_t)s3 * 64)[lane];
        uint2 p4 = reinterpret_cast<const uint2*>(hn + (size_t)s4 * 64)[lane];
        uint2 p5 = reinterpret_cast<const uint2*>(hn + (size_t)s5 * 64)[lane];
        uint2 p6 = reinterpret_cast<const uint2*>(hn + (size_t)s6 * 64)[lane];
        uint2 p7 = reinterpret_cast<const uint2*>(hn + (size_t)s7 * 64)[lane];
        a0 += bf_lo(p0.x) + bf_lo(p1.x) + bf_lo(p2.x) + bf_lo(p3.x)
            + bf_lo(p4.x) + bf_lo(p5.x) + bf_lo(p6.x) + bf_lo(p7.x);
        a1 += bf_hi(p0.x) + bf_hi(p1.x) + bf_hi(p2.x) + bf_hi(p3.x)
            + bf_hi(p4.x) + bf_hi(p5.x) + bf_hi(p6.x) + bf_hi(p7.x);
        a2 += bf_lo(p0.y) + bf_lo(p1.y) + bf_lo(p2.y) + bf_lo(p3.y)
            + bf_lo(p4.y) + bf_lo(p5.y) + bf_lo(p6.y) + bf_lo(p7.y);
        a3 += bf_hi(p0.y) + bf_hi(p1.y) + bf_hi(p2.y) + bf_hi(p3.y)
            + bf_hi(p4.y) + bf_hi(p5.y) + bf_hi(p6.y) + bf_hi(p7.y);
    }
    for (; i + 4 <= end; i += 4) {
        int s0 = csr_src[i + 0], s1 = csr_src[i + 1];
        int s2 = csr_src[i + 2], s3 = csr_src[i + 3];
        uint2 p0 = reinterpret_cast<const uint2*>(hn + (size_t)s0 * 64)[lane];
        uint2 p1 = reinterpret_cast<const uint2*>(hn + (size_t)s1 * 64)[lane];
        uint2 p2 = reinterpret_cast<const uint2*>(hn + (size_t)s2 * 64)[lane];
        uint2 p3 = reinterpret_cast<const uint2*>(hn + (size_t)s3 * 64)[lane];
        a0 += bf_lo(p0.x) + bf_lo(p1.x) + bf_lo(p2.x) + bf_lo(p3.x);
        a1 += bf_hi(p0.x) + bf_hi(p1.x) + bf_hi(p2.x) + bf_hi(p3.x);
        a2 += bf_lo(p0.y) + bf_lo(p1.y) + bf_lo(p2.y) + bf_lo(p3.y);
        a3 += bf_hi(p0.y) + bf_hi(p1.y) + bf_hi(p2.y) + bf_hi(p3.y);
    }
    for (; i < end; ++i) {
        uint2 p = reinterpret_cast<const uint2*>(hn + (size_t)csr_src[i] * 64)[lane];
        a0 += bf_lo(p.x); a1 += bf_hi(p.x); a2 += bf_lo(p.y); a3 += bf_hi(p.y);
    }
    float nd = norm[node];
    float e1 = 1.0f + eps[0];
    float4 hv = reinterpret_cast<const float4*>(h + (size_t)node * D_FEAT)[lane];
    float4 o;
    o.x = (e1 * hv.x * nd + a0) * nd;
    o.y = (e1 * hv.y * nd + a1) * nd;
    o.z = (e1 * hv.z * nd + a2) * nd;
    o.w = (e1 * hv.w * nd + a3) * nd;
    reinterpret_cast<float4*>(out + (size_t)node * D_FEAT)[lane] = o;
}

// ---------------- fallback (atomic scatter) ----------------
__global__ void gin_init(const float* __restrict__ h, const float* __restrict__ norm,
                         const float* __restrict__ eps, float* __restrict__ out,
                         int n_nodes) {
    int i = blockIdx.x * blockDim.x + threadIdx.x;
    int total = n_nodes * (D_FEAT / 4);
    if (i >= total) return;
    int node = i / (D_FEAT / 4);
    float nm = norm[node];
    float scale = (1.0f + eps[0]) * nm * nm;
    const float4* h4 = reinterpret_cast<const float4*>(h);
    float4* o4 = reinterpret_cast<float4*>(out);
    float4 v = h4[i];
    v.x *= scale; v.y *= scale; v.z *= scale; v.w *= scale;
    o4[i] = v;
}

__global__ void gin_edge(const float* __restrict__ h, const float* __restrict__ norm,
                         const int* __restrict__ src, const int* __restrict__ dst,
                         float* __restrict__ out, int n_edges) {
    long long t = (long long)blockIdx.x * blockDim.x + threadIdx.x;
    int e = (int)(t >> 5);
    int lane = (int)(t & 31);
    if (e >= n_edges) return;
    int s = src[e], d = dst[e];
    float coef = norm[s] * norm[d];
    const float4* hs = reinterpret_cast<const float4*>(h + (long long)s * D_FEAT);
    float4 v = hs[lane];
    float* od = out + (long long)d * D_FEAT + lane * 4;
    atomicAdd(od + 0, v.x * coef);
    atomicAdd(od + 1, v.y * coef);
    atomicAdd(od + 2, v.z * coef);
    atomicAdd(od + 3, v.w * coef);
}

extern "C" void kernel_launch(void* const* d_in, const int* in_sizes, int n_in,
                              void* d_out, int out_size, void* d_ws, size_t ws_size,
                              hipStream_t stream) {
    const float* h    = (const float*)d_in[0];
    const float* norm = (const float*)d_in[1];
    const float* eps  = (const float*)d_in[2];
    const int*   src  = (const int*)d_in[3];
    const int*   dst  = (const int*)d_in[4];
    float* out = (float*)d_out;

    int n_nodes = in_sizes[1];
    int n_edges = in_sizes[3];
    int nb = (n_nodes + 1023) / 1024;

    size_t hn_words = (size_t)n_nodes * (D_FEAT / 2);
    size_t need = (hn_words + (size_t)n_nodes          // counts
                   + (size_t)(n_nodes + 1)             // offs
                   + (size_t)n_nodes                   // cursor
                   + (size_t)n_edges) * 4;             // csr_src

    int e4 = n_edges >> 2;
    int eb4 = (e4 + 1 + 255) / 256;                    // +1 thread for tail
    int zb = (n_nodes + 255) / 256;
    int gb = (n_nodes + 7) / 8;
    int pre_threads = n_nodes * (D_FEAT / 4);

    if (ws_size >= need) {
        u32* hn      = (u32*)d_ws;
        int* counts  = (int*)(hn + hn_words);
        int* offs    = counts + n_nodes;               // FINAL offsets
        int* cursor  = offs + (n_nodes + 1);
        int* csr_src = cursor + n_nodes;

        zero_counts<<<zb, 256, 0, stream>>>(counts, n_nodes);
        deg_hn<<<eb4, 256, 0, stream>>>(dst, counts, h, norm, hn, n_edges, n_nodes);
        scan_onepass<<<nb, 1024, 0, stream>>>(counts, offs, cursor, n_nodes, nb);
        scatter_csr4<<<eb4, 256, 0, stream>>>(src, dst, cursor, csr_src, n_edges);
        gather_bf16_v3<<<gb, 256, 0, stream>>>(h, norm, eps, offs, csr_src, hn,
                                               out, n_nodes);
    } else {
        gin_init<<<(pre_threads + 255) / 256, 256, 0, stream>>>(h, norm, eps, out, n_nodes);
        long long et = (long long)n_edges * 32;
        gin_edge<<<(int)((et + 255) / 256), 256, 0, stream>>>(h, norm, src, dst, out, n_edges);
    }
}

// Round 10
// 104.340 us; speedup vs baseline: 1.3457x; 1.3457x over previous
//
#include <hip/hip_runtime.h>

#define D_FEAT 128

typedef unsigned int u32;

__device__ __forceinline__ u32 f2bf_pack(float a, float b) {
    u32 ua = __float_as_uint(a);
    u32 ub = __float_as_uint(b);
    ua = (ua + 0x7fffu + ((ua >> 16) & 1u)) >> 16;   // RNE to bf16
    ub = (ub + 0x7fffu + ((ub >> 16) & 1u)) >> 16;
    return ua | (ub << 16);
}

__device__ __forceinline__ float bf_lo(u32 p) { return __uint_as_float(p << 16); }
__device__ __forceinline__ float bf_hi(u32 p) { return __uint_as_float(p & 0xffff0000u); }

// K0: zero the histogram
__global__ void zero_counts(int* __restrict__ counts, int n) {
    int i = blockIdx.x * 256 + threadIdx.x;
    if (i < n) counts[i] = 0;
}

// K1: return-atomic histogram capturing per-edge rank, with the hn=bf16(h*norm)
// streaming work placed BETWEEN atomic issue and rank store, so the ~800cy
// atomic round trip hides under ~500+ cycles of independent streaming.
__global__ void deg_rank_hn(const int* __restrict__ dst, int* __restrict__ counts,
                            int* __restrict__ rank,
                            const float* __restrict__ h, const float* __restrict__ norm,
                            u32* __restrict__ hn, int n_edges, int n_nodes) {
    int gsize = gridDim.x * 256;
    int t = blockIdx.x * 256 + threadIdx.x;
    bool have = (t < n_edges);
    int r = 0;
    if (have) r = atomicAdd(&counts[dst[t]], 1);     // issue early
    // independent streaming: hn precompute (2 iters/thread at this grid size)
    int total4 = n_nodes * (D_FEAT / 4);
    for (int j = t; j < total4; j += gsize) {
        int node = j >> 5;
        float nm = norm[node];
        float4 v = reinterpret_cast<const float4*>(h)[j];
        uint2 o;
        o.x = f2bf_pack(v.x * nm, v.y * nm);
        o.y = f2bf_pack(v.z * nm, v.w * nm);
        reinterpret_cast<uint2*>(hn)[j] = o;
    }
    if (have) rank[t] = r;                           // consume late
}

// K2: one-dispatch exclusive scan; block b re-sums chunks [0,b) for its carry,
// then scans its own 1024-elem chunk; writes FINAL offsets.
__global__ void __launch_bounds__(1024)
scan_onepass(const int* __restrict__ counts, int* __restrict__ offs, int n, int nb) {
    __shared__ int smem[1024];
    int tid = threadIdx.x;
    int b = blockIdx.x;
    int lim = b << 10;
    int part = 0;
    for (int j = tid; j < lim; j += 1024) part += counts[j];
    smem[tid] = part;
    __syncthreads();
    for (int off = 512; off > 0; off >>= 1) {
        if (tid < off) smem[tid] += smem[tid + off];
        __syncthreads();
    }
    int carry = smem[0];
    __syncthreads();
    int idx = lim + tid;
    int v = (idx < n) ? counts[idx] : 0;
    smem[tid] = v;
    __syncthreads();
    for (int off = 1; off < 1024; off <<= 1) {
        int t = (tid >= off) ? smem[tid - off] : 0;
        __syncthreads();
        smem[tid] += t;
        __syncthreads();
    }
    if (idx < n) offs[idx] = carry + smem[tid] - v;
    if (b == nb - 1 && tid == 1023) offs[n] = carry + smem[1023];
}

// K3: atomic-free scatter using final offs + precomputed rank
__global__ void scatter_rank(const int* __restrict__ src, const int* __restrict__ dst,
                             const int* __restrict__ offs, const int* __restrict__ rank,
                             int* __restrict__ csr_src, int n_edges) {
    int i = blockIdx.x * blockDim.x + threadIdx.x;
    if (i < n_edges) csr_src[offs[dst[i]] + rank[i]] = src[i];
}

// K4: gather. 32 lanes per node (2 nodes/wave), uint2 per lane = full 256B
// bf16 row per instruction; unroll 8.
__global__ void gather_bf16_v3(const float* __restrict__ h,
                               const float* __restrict__ norm,
                               const float* __restrict__ eps,
                               const int* __restrict__ offs,
                               const int* __restrict__ csr_src,
                               const u32* __restrict__ hn,
                               float* __restrict__ out, int n_nodes) {
    int t = blockIdx.x * 256 + threadIdx.x;
    int node = t >> 5;
    int lane = t & 31;
    if (node >= n_nodes) return;
    int beg = offs[node];
    int end = offs[node + 1];
    float a0 = 0.0f, a1 = 0.0f, a2 = 0.0f, a3 = 0.0f;
    int i = beg;
    for (; i + 8 <= end; i += 8) {
        int s0 = csr_src[i + 0], s1 = csr_src[i + 1];
        int s2 = csr_src[i + 2], s3 = csr_src[i + 3];
        int s4 = csr_src[i + 4], s5 = csr_src[i + 5];
        int s6 = csr_src[i + 6], s7 = csr_src[i + 7];
        uint2 p0 = reinterpret_cast<const uint2*>(hn + (size_t)s0 * 64)[lane];
        uint2 p1 = reinterpret_cast<const uint2*>(hn + (size_t)s1 * 64)[lane];
        uint2 p2 = reinterpret_cast<const uint2*>(hn + (size_t)s2 * 64)[lane];
        uint2 p3 = reinterpret_cast<const uint2*>(hn + (size_t)s3 * 64)[lane];
        uint2 p4 = reinterpret_cast<const uint2*>(hn + (size_t)s4 * 64)[lane];
        uint2 p5 = reinterpret_cast<const uint2*>(hn + (size_t)s5 * 64)[lane];
        uint2 p6 = reinterpret_cast<const uint2*>(hn + (size_t)s6 * 64)[lane];
        uint2 p7 = reinterpret_cast<const uint2*>(hn + (size_t)s7 * 64)[lane];
        a0 += bf_lo(p0.x) + bf_lo(p1.x) + bf_lo(p2.x) + bf_lo(p3.x)
            + bf_lo(p4.x) + bf_lo(p5.x) + bf_lo(p6.x) + bf_lo(p7.x);
        a1 += bf_hi(p0.x) + bf_hi(p1.x) + bf_hi(p2.x) + bf_hi(p3.x)
            + bf_hi(p4.x) + bf_hi(p5.x) + bf_hi(p6.x) + bf_hi(p7.x);
        a2 += bf_lo(p0.y) + bf_lo(p1.y) + bf_lo(p2.y) + bf_lo(p3.y)
            + bf_lo(p4.y) + bf_lo(p5.y) + bf_lo(p6.y) + bf_lo(p7.y);
        a3 += bf_hi(p0.y) + bf_hi(p1.y) + bf_hi(p2.y) + bf_hi(p3.y)
            + bf_hi(p4.y) + bf_hi(p5.y) + bf_hi(p6.y) + bf_hi(p7.y);
    }
    for (; i + 4 <= end; i += 4) {
        int s0 = csr_src[i + 0], s1 = csr_src[i + 1];
        int s2 = csr_src[i + 2], s3 = csr_src[i + 3];
        uint2 p0 = reinterpret_cast<const uint2*>(hn + (size_t)s0 * 64)[lane];
        uint2 p1 = reinterpret_cast<const uint2*>(hn + (size_t)s1 * 64)[lane];
        uint2 p2 = reinterpret_cast<const uint2*>(hn + (size_t)s2 * 64)[lane];
        uint2 p3 = reinterpret_cast<const uint2*>(hn + (size_t)s3 * 64)[lane];
        a0 += bf_lo(p0.x) + bf_lo(p1.x) + bf_lo(p2.x) + bf_lo(p3.x);
        a1 += bf_hi(p0.x) + bf_hi(p1.x) + bf_hi(p2.x) + bf_hi(p3.x);
        a2 += bf_lo(p0.y) + bf_lo(p1.y) + bf_lo(p2.y) + bf_lo(p3.y);
        a3 += bf_hi(p0.y) + bf_hi(p1.y) + bf_hi(p2.y) + bf_hi(p3.y);
    }
    for (; i < end; ++i) {
        uint2 p = reinterpret_cast<const uint2*>(hn + (size_t)csr_src[i] * 64)[lane];
        a0 += bf_lo(p.x); a1 += bf_hi(p.x); a2 += bf_lo(p.y); a3 += bf_hi(p.y);
    }
    float nd = norm[node];
    float e1 = 1.0f + eps[0];
    float4 hv = reinterpret_cast<const float4*>(h + (size_t)node * D_FEAT)[lane];
    float4 o;
    o.x = (e1 * hv.x * nd + a0) * nd;
    o.y = (e1 * hv.y * nd + a1) * nd;
    o.z = (e1 * hv.z * nd + a2) * nd;
    o.w = (e1 * hv.w * nd + a3) * nd;
    reinterpret_cast<float4*>(out + (size_t)node * D_FEAT)[lane] = o;
}

// ---------------- fallback (atomic scatter) ----------------
__global__ void gin_init(const float* __restrict__ h, const float* __restrict__ norm,
                         const float* __restrict__ eps, float* __restrict__ out,
                         int n_nodes) {
    int i = blockIdx.x * blockDim.x + threadIdx.x;
    int total = n_nodes * (D_FEAT / 4);
    if (i >= total) return;
    int node = i / (D_FEAT / 4);
    float nm = norm[node];
    float scale = (1.0f + eps[0]) * nm * nm;
    const float4* h4 = reinterpret_cast<const float4*>(h);
    float4* o4 = reinterpret_cast<float4*>(out);
    float4 v = h4[i];
    v.x *= scale; v.y *= scale; v.z *= scale; v.w *= scale;
    o4[i] = v;
}

__global__ void gin_edge(const float* __restrict__ h, const float* __restrict__ norm,
                         const int* __restrict__ src, const int* __restrict__ dst,
                         float* __restrict__ out, int n_edges) {
    long long t = (long long)blockIdx.x * blockDim.x + threadIdx.x;
    int e = (int)(t >> 5);
    int lane = (int)(t & 31);
    if (e >= n_edges) return;
    int s = src[e], d = dst[e];
    float coef = norm[s] * norm[d];
    const float4* hs = reinterpret_cast<const float4*>(h + (long long)s * D_FEAT);
    float4 v = hs[lane];
    float* od = out + (long long)d * D_FEAT + lane * 4;
    atomicAdd(od + 0, v.x * coef);
    atomicAdd(od + 1, v.y * coef);
    atomicAdd(od + 2, v.z * coef);
    atomicAdd(od + 3, v.w * coef);
}

extern "C" void kernel_launch(void* const* d_in, const int* in_sizes, int n_in,
                              void* d_out, int out_size, void* d_ws, size_t ws_size,
                              hipStream_t stream) {
    const float* h    = (const float*)d_in[0];
    const float* norm = (const float*)d_in[1];
    const float* eps  = (const float*)d_in[2];
    const int*   src  = (const int*)d_in[3];
    const int*   dst  = (const int*)d_in[4];
    float* out = (float*)d_out;

    int n_nodes = in_sizes[1];
    int n_edges = in_sizes[3];
    int nb = (n_nodes + 1023) / 1024;

    size_t hn_words = (size_t)n_nodes * (D_FEAT / 2);
    size_t need = (hn_words + (size_t)n_nodes           // counts
                   + (size_t)(n_nodes + 1)              // offs
                   + 2 * (size_t)n_edges) * 4;          // rank + csr_src

    int eb = (n_edges + 255) / 256;
    int zb = (n_nodes + 255) / 256;
    int gb = (n_nodes + 7) / 8;
    int pre_threads = n_nodes * (D_FEAT / 4);

    if (ws_size >= need) {
        u32* hn      = (u32*)d_ws;
        int* counts  = (int*)(hn + hn_words);
        int* offs    = counts + n_nodes;                // FINAL offsets
        int* rank    = offs + (n_nodes + 1);
        int* csr_src = rank + n_edges;

        zero_counts<<<zb, 256, 0, stream>>>(counts, n_nodes);
        deg_rank_hn<<<eb, 256, 0, stream>>>(dst, counts, rank, h, norm, hn,
                                            n_edges, n_nodes);
        scan_onepass<<<nb, 1024, 0, stream>>>(counts, offs, n_nodes, nb);
        scatter_rank<<<eb, 256, 0, stream>>>(src, dst, offs, rank, csr_src, n_edges);
        gather_bf16_v3<<<gb, 256, 0, stream>>>(h, norm, eps, offs, csr_src, hn,
                                               out, n_nodes);
    } else {
        gin_init<<<(pre_threads + 255) / 256, 256, 0, stream>>>(h, norm, eps, out, n_nodes);
        long long et = (long long)n_edges * 32;
        gin_edge<<<(int)((et + 255) / 256), 256, 0, stream>>>(h, norm, src, dst, out, n_edges);
    }
}